// Round 14
// baseline (307.326 us; speedup 1.0000x reference)
//
#include <hip/hip_runtime.h>

typedef __bf16 bf16x8 __attribute__((ext_vector_type(8)));
typedef float f32x4 __attribute__((ext_vector_type(4)));
typedef float f32x16 __attribute__((ext_vector_type(16)));
typedef short short4v __attribute__((ext_vector_type(4)));
typedef unsigned short ushort8 __attribute__((ext_vector_type(8)));
typedef unsigned int uint4v __attribute__((ext_vector_type(4)));

#define AS1 __attribute__((address_space(1)))
#define AS3 __attribute__((address_space(3)))
#define GLL16(g, l) __builtin_amdgcn_global_load_lds((const AS1 void*)(g), (AS3 void*)(l), 16, 0, 0)
#define MFMA16(a, b, c) __builtin_amdgcn_mfma_f32_16x16x32_bf16((a), (b), (c), 0, 0, 0)
#define MFMA32(a, b, c) __builtin_amdgcn_mfma_f32_32x32x16_bf16((a), (b), (c), 0, 0, 0)
#define L2E 1.44269504f

__device__ __forceinline__ unsigned short f2bf(float f) {
  unsigned int u = __builtin_bit_cast(unsigned int, f);
  u = (u + 0x7fffu + ((u >> 16) & 1u)) >> 16;
  return (unsigned short)u;
}

__device__ __forceinline__ unsigned int cvtpk_bf16(float lo, float hi) {
  unsigned int r;
  asm("v_cvt_pk_bf16_f32 %0, %1, %2" : "=v"(r) : "v"(lo), "v"(hi));
  return r;
}

// ---------------- convert: f32 -> bf16 (x, concat weights, w_o) ----------------
__global__ void convert_kernel(const float* __restrict__ x,
                               const float* __restrict__ w_qt, const float* __restrict__ w_kt,
                               const float* __restrict__ w_qs, const float* __restrict__ w_ks,
                               const float* __restrict__ w_v, const float* __restrict__ w_o,
                               unsigned short* __restrict__ xb, unsigned short* __restrict__ wcat,
                               unsigned short* __restrict__ wob) {
  const int NX = 4096 * 1024, NW = 3072 * 1024, NO = 1024 * 1024;
  int stride = gridDim.x * blockDim.x;
  for (int i = blockIdx.x * blockDim.x + threadIdx.x; i < NX + NW + NO; i += stride) {
    if (i < NX) {
      xb[i] = f2bf(x[i]);
    } else if (i < NX + NW) {
      int j = i - NX;
      int n = j >> 10, k = j & 1023;
      const float* src;
      if (n < 256)        src = w_qt + n * 1024;
      else if (n < 1024)  src = w_qs + (n - 256) * 1024;
      else if (n < 1280)  src = w_kt + (n - 1024) * 1024;
      else if (n < 2048)  src = w_ks + (n - 1280) * 1024;
      else                src = w_v + (n - 2048) * 1024;
      wcat[j] = f2bf(src[k]);
    } else {
      int j = i - NX - NW;
      wob[j] = f2bf(w_o[j]);
    }
  }
}

// ---------------- GEMM 1: X*(Wq|Wk|Wv)^T -> Q (B,H,L,64), Kfrag, Vfrag (MFMA-fragment layout) ----------------
// kfrag[bh][cg][m][lane][e]: element = K[bh][cg*32 + (lane&31)][m*16 + (lane>>5)*8 + e]
// vfrag[bh][cg][kh*2+dh][lane][e]: element = V'[bh][cg*32 + kh*16 + (lane>>5)*8 + e][dh*32 + (lane&31)]
//   (V' = V * e^mask, folded)
// K-range blocks (blockIdx.y in [8,16)) use SWAPPED mfma operand order so the token rides the
// lane and each acc reg holds 4 consecutive features -> one short4v store per reg.
__global__ __launch_bounds__(256) void gemm_qkv(const unsigned short* __restrict__ A,
                                                const unsigned short* __restrict__ Bw,
                                                const float* __restrict__ amask,
                                                unsigned short* __restrict__ qb,
                                                unsigned short* __restrict__ kfrag,
                                                unsigned short* __restrict__ vfrag) {
  __shared__ unsigned short As[128 * 32];
  __shared__ unsigned short Bs[128 * 32];
  const int t = threadIdx.x;
  const int lane = t & 63, wid = t >> 6;
  const int wm = wid >> 1, wn = wid & 1;
  const int lr = lane & 15, lg = lane >> 4;
  const int m0 = blockIdx.x * 128, n0 = blockIdx.y * 128;
  const bool swapK = (blockIdx.y >= 8) && (blockIdx.y < 16);
  const int K = 1024;
  f32x4 acc[4][4] = {};
  const unsigned short* gA0 = A + (m0 + (t >> 2)) * K + (t & 3) * 8;
  const unsigned short* gB0 = Bw + (n0 + (t >> 2)) * K + (t & 3) * 8;
  char* lA = (char*)As + wid * 1024;
  char* lB = (char*)Bs + wid * 1024;
  for (int k0 = 0; k0 < K; k0 += 32) {
    __syncthreads();
    GLL16(gA0 + k0, lA);
    GLL16(gA0 + 64 * K + k0, lA + 4096);
    GLL16(gB0 + k0, lB);
    GLL16(gB0 + 64 * K + k0, lB + 4096);
    __syncthreads();
    bf16x8 af[4], bfr[4];
#pragma unroll
    for (int i = 0; i < 4; ++i) {
      af[i] = *(const bf16x8*)&As[(wm * 64 + i * 16 + lr) * 32 + lg * 8];
      bfr[i] = *(const bf16x8*)&Bs[(wn * 64 + i * 16 + lr) * 32 + lg * 8];
    }
    if (swapK) {
#pragma unroll
      for (int i = 0; i < 4; ++i)
#pragma unroll
        for (int j = 0; j < 4; ++j)
          acc[i][j] = MFMA16(bfr[j], af[i], acc[i][j]);
    } else {
#pragma unroll
      for (int i = 0; i < 4; ++i)
#pragma unroll
        for (int j = 0; j < 4; ++j)
          acc[i][j] = MFMA16(af[i], bfr[j], acc[i][j]);
    }
  }
  if (blockIdx.y < 8) {
    // Q: (B,H,L,64); D col=lane -> feature n, rows -> tokens
#pragma unroll
    for (int i = 0; i < 4; ++i) {
#pragma unroll
      for (int j = 0; j < 4; ++j) {
        int n = n0 + wn * 64 + j * 16 + lr;
        int mb = m0 + wm * 64 + i * 16 + lg * 4;
        int b = mb >> 11, l = mb & 2047;
        int h = n >> 6, d = n & 63;
        f32x4 v = acc[i][j];
#pragma unroll
        for (int r = 0; r < 4; ++r)
          qb[((b * 16 + h) * 2048 + l + r) * 64 + d] = f2bf(v[r]);
      }
    }
  } else if (swapK) {
    // K fragment, swapped orientation: lane -> token, regs -> 4 consecutive features
#pragma unroll
    for (int i = 0; i < 4; ++i) {
#pragma unroll
      for (int j = 0; j < 4; ++j) {
        int m = m0 + wm * 64 + i * 16 + lr;            // token
        int bb = m >> 11, l = m & 2047;
        int nn = (n0 - 1024) + wn * 64 + j * 16 + lg * 4;  // feature base (+r)
        int h = nn >> 6, d0 = nn & 63;
        int mfr = d0 >> 4, hi2 = (d0 >> 3) & 1, e0 = d0 & 7;
        size_t idx = ((size_t)((bb * 16 + h) * 64 + (l >> 5)) * 4 + mfr) * 512
                     + (hi2 * 32 + (l & 31)) * 8 + e0;
        f32x4 v = acc[i][j];
        short4v pk;
        pk[0] = (short)f2bf(v[0]); pk[1] = (short)f2bf(v[1]);
        pk[2] = (short)f2bf(v[2]); pk[3] = (short)f2bf(v[3]);
        *(short4v*)&kfrag[idx] = pk;
      }
    }
  } else {
    // V' fragment layout (scaled by e^mask); 4 tokens contiguous within one lane's 8 elems
#pragma unroll
    for (int i = 0; i < 4; ++i) {
#pragma unroll
      for (int j = 0; j < 4; ++j) {
        int n = n0 + wn * 64 + j * 16 + lr;
        int mb = m0 + wm * 64 + i * 16 + lg * 4;
        int b = mb >> 11, l = mb & 2047;
        int nn = n - 2048;
        int h = nn >> 6, d = nn & 63;
        int dh = d >> 5, dcol = d & 31;
        int kk = l & 31;
        int kh = kk >> 4, hi2 = (kk >> 3) & 1, i0 = kk & 7;
        const float* mrow = amask + b * 2048 + l;
        size_t idx = ((size_t)((b * 16 + h) * 64 + (l >> 5)) * 4 + (kh * 2 + dh)) * 512
                     + (hi2 * 32 + dcol) * 8 + i0;
        f32x4 v = acc[i][j];
        short4v pk;
#pragma unroll
        for (int r = 0; r < 4; ++r)
          pk[r] = (short)f2bf(v[r] * __expf(mrow[r]));
        *(short4v*)&vfrag[idx] = pk;
      }
    }
  }
}

// ---------------- attention v14: r9 structure + s_setprio around MFMA clusters ----------------
// Block = 32 q-rows of one bh; 4 waves, wave w owns tiles cg in [w*16, w*16+16).
__global__ __launch_bounds__(256, 3) void attn_kernel(const unsigned short* __restrict__ qb,
                                                      const unsigned short* __restrict__ kfrag,
                                                      const unsigned short* __restrict__ vfrag,
                                                      const float* __restrict__ mask,
                                                      const float* __restrict__ w_sigma,
                                                      float* __restrict__ probs,
                                                      unsigned short* __restrict__ ao) {
  __shared__ __align__(16) float pvacc[2048];
  __shared__ float psum[4][32];
  __shared__ float rsum[32];
  const int t = threadIdx.x;
  const int lane = t & 63, w = t >> 6;
  const int col = lane & 31, hi = lane >> 5;
  const int s = blockIdx.x;
  const int bh = (s & 7) * 4 + ((s >> 3) >> 6);
  const int q0 = ((s >> 3) & 63) * 32;
  const int b = bh >> 4, h = bh & 15;
  const float sigma = 1.0f / (1.0f + __expf(-w_sigma[0]));
  const float fac2 = ((h < 4) ? (-sigma * 0.125f) : 0.125f) * L2E;
  const float* maskb = mask + b * 2048;
  const int cg0 = w * 16;

  const unsigned short* kfb = kfrag + (size_t)bh * 131072;
  const unsigned short* vfb = vfrag + (size_t)bh * 131072;

  for (int i = t; i < 2048; i += 256) pvacc[i] = 0.0f;

  // Q fragments (one-time gather)
  bf16x8 qf[4];
  {
    const unsigned short* qp = qb + (size_t)(bh * 2048 + q0 + col) * 64 + hi * 8;
#pragma unroll
    for (int m = 0; m < 4; ++m) qf[m] = *(const bf16x8*)(qp + m * 16);
  }

  // ---- pass 1: rowsums ----
  float rs[16];
#pragma unroll
  for (int r = 0; r < 16; ++r) rs[r] = 0.f;
  for (int c = 0; c < 16; ++c) {
    int cg = cg0 + c;
    const unsigned short* kp = kfb + (size_t)cg * 2048 + lane * 8;
    bf16x8 kf0 = *(const bf16x8*)(kp);
    bf16x8 kf1 = *(const bf16x8*)(kp + 512);
    bf16x8 kf2 = *(const bf16x8*)(kp + 1024);
    bf16x8 kf3 = *(const bf16x8*)(kp + 1536);
    float mv2 = maskb[cg * 32 + col] * L2E;
    __builtin_amdgcn_s_setprio(1);
    f32x16 sacc = {};
    sacc = MFMA32(qf[0], kf0, sacc);
    sacc = MFMA32(qf[1], kf1, sacc);
    sacc = MFMA32(qf[2], kf2, sacc);
    sacc = MFMA32(qf[3], kf3, sacc);
    __builtin_amdgcn_s_setprio(0);
#pragma unroll
    for (int r = 0; r < 16; ++r) rs[r] += exp2f(sacc[r] * fac2 + mv2);
  }
#pragma unroll
  for (int o = 1; o < 32; o <<= 1)
#pragma unroll
    for (int r = 0; r < 16; ++r) rs[r] += __shfl_xor(rs[r], o);
  if (col == 0) {
#pragma unroll
    for (int r = 0; r < 16; ++r) psum[w][(r & 3) + 8 * (r >> 2) + 4 * hi] = rs[r];
  }
  __syncthreads();
  if (t < 32) rsum[t] = -log2f(psum[0][t] + psum[1][t] + psum[2][t] + psum[3][t]);
  __syncthreads();

  float rws_l[16];
#pragma unroll
  for (int r = 0; r < 16; ++r) rws_l[r] = rsum[(r & 3) + 8 * (r >> 2) + 4 * hi];
  const float rws_t = rsum[col];

  // ---- pass 2: dual-orientation QK, direct probs stores, in-reg PV fragments ----
  f32x16 oacc0 = {}, oacc1 = {};
  float* pp = probs + (size_t)(bh * 2048 + q0) * 2048;
  for (int c = 0; c < 16; ++c) {
    int cg = cg0 + c;
    const unsigned short* kp = kfb + (size_t)cg * 2048 + lane * 8;
    const unsigned short* vp = vfb + (size_t)cg * 2048 + lane * 8;
    bf16x8 kf0 = *(const bf16x8*)(kp);
    bf16x8 kf1 = *(const bf16x8*)(kp + 512);
    bf16x8 kf2 = *(const bf16x8*)(kp + 1024);
    bf16x8 kf3 = *(const bf16x8*)(kp + 1536);
    bf16x8 vf0 = *(const bf16x8*)(vp);
    bf16x8 vf1 = *(const bf16x8*)(vp + 512);
    bf16x8 vf2 = *(const bf16x8*)(vp + 1024);
    bf16x8 vf3 = *(const bf16x8*)(vp + 1536);
    float mv2 = maskb[cg * 32 + col] * L2E;
    __builtin_amdgcn_s_setprio(1);
    f32x16 sn = {}, st_ = {};
    sn = MFMA32(qf[0], kf0, sn);  st_ = MFMA32(kf0, qf[0], st_);
    sn = MFMA32(qf[1], kf1, sn);  st_ = MFMA32(kf1, qf[1], st_);
    sn = MFMA32(qf[2], kf2, sn);  st_ = MFMA32(kf2, qf[2], st_);
    sn = MFMA32(qf[3], kf3, sn);  st_ = MFMA32(kf3, qf[3], st_);
    __builtin_amdgcn_s_setprio(0);
    // n-side: normalized probs (exact mask)
    float pn[16];
#pragma unroll
    for (int r = 0; r < 16; ++r) pn[r] = exp2f(sn[r] * fac2 + (rws_l[r] + mv2));
    // t-side: mask folded into V'; clamp for general-mask safety
    float pt[16];
#pragma unroll
    for (int r = 0; r < 16; ++r) pt[r] = exp2f(fminf(st_[r] * fac2 + rws_t, 60.0f));
    unsigned int A0 = cvtpk_bf16(pt[0], pt[1]),   B0 = cvtpk_bf16(pt[4], pt[5]);
    unsigned int C0 = cvtpk_bf16(pt[2], pt[3]),   D0 = cvtpk_bf16(pt[6], pt[7]);
    unsigned int E0 = cvtpk_bf16(pt[8], pt[9]),   F0 = cvtpk_bf16(pt[12], pt[13]);
    unsigned int G0 = cvtpk_bf16(pt[10], pt[11]), H0 = cvtpk_bf16(pt[14], pt[15]);
    asm("v_permlane32_swap_b32 %0, %1" : "+v"(A0), "+v"(B0));
    asm("v_permlane32_swap_b32 %0, %1" : "+v"(C0), "+v"(D0));
    asm("v_permlane32_swap_b32 %0, %1" : "+v"(E0), "+v"(F0));
    asm("v_permlane32_swap_b32 %0, %1" : "+v"(G0), "+v"(H0));
    uint4v u1; u1[0] = A0; u1[1] = C0; u1[2] = B0; u1[3] = D0;
    uint4v u2; u2[0] = E0; u2[1] = G0; u2[2] = F0; u2[3] = H0;
    bf16x8 frag1 = __builtin_bit_cast(bf16x8, u1);
    bf16x8 frag2 = __builtin_bit_cast(bf16x8, u2);
    // PV: oacc[dh] += frag[kh] * vf[kh*2+dh]
    __builtin_amdgcn_s_setprio(1);
    oacc0 = MFMA32(frag1, vf0, oacc0);
    oacc1 = MFMA32(frag1, vf1, oacc1);
    oacc0 = MFMA32(frag2, vf2, oacc0);
    oacc1 = MFMA32(frag2, vf3, oacc1);
    __builtin_amdgcn_s_setprio(0);
    // probs stores (two 128B segments per instr)
    float* pr = pp + cg * 32 + col;
#pragma unroll
    for (int r = 0; r < 16; ++r) {
      int row = (r & 3) + 8 * (r >> 2) + 4 * hi;
      __builtin_nontemporal_store(pn[r], pr + (size_t)row * 2048);
    }
  }

  // ---- merge PV partials across waves ----
  __syncthreads();
#pragma unroll
  for (int r = 0; r < 16; ++r) {
    int row = (r & 3) + 8 * (r >> 2) + 4 * hi;
    atomicAdd(&pvacc[row * 64 + col], oacc0[r]);
    atomicAdd(&pvacc[row * 64 + 32 + col], oacc1[r]);
  }
  __syncthreads();
  {
    int row = t >> 3, c8 = (t & 7) * 8;
    f32x4 v0 = *(const f32x4*)&pvacc[row * 64 + c8];
    f32x4 v1 = *(const f32x4*)&pvacc[row * 64 + c8 + 4];
    ushort8 o;
#pragma unroll
    for (int i = 0; i < 4; ++i) {
      o[i] = f2bf(v0[i]);
      o[i + 4] = f2bf(v1[i]);
    }
    *(ushort8*)&ao[((b * 2048) + q0 + row) * 1024 + h * 64 + c8] = o;
  }
}

// ---------------- GEMM 2: AO(4096x1024) * Wo(1024x1024)^T -> out f32 ----------------
__global__ __launch_bounds__(256) void gemm_oproj(const unsigned short* __restrict__ A,
                                                  const unsigned short* __restrict__ Bw,
                                                  float* __restrict__ out) {
  __shared__ unsigned short As[128 * 32];
  __shared__ unsigned short Bs[128 * 32];
  const int t = threadIdx.x;
  const int lane = t & 63, wid = t >> 6;
  const int wm = wid >> 1, wn = wid & 1;
  const int lr = lane & 15, lg = lane >> 4;
  const int m0 = blockIdx.x * 128, n0 = blockIdx.y * 128;
  const int K = 1024;
  f32x4 acc[4][4] = {};
  const unsigned short* gA0 = A + (m0 + (t >> 2)) * K + (t & 3) * 8;
  const unsigned short* gB0 = Bw + (n0 + (t >> 2)) * K + (t & 3) * 8;
  char* lA = (char*)As + wid * 1024;
  char* lB = (char*)Bs + wid * 1024;
  for (int k0 = 0; k0 < K; k0 += 32) {
    __syncthreads();
    GLL16(gA0 + k0, lA);
    GLL16(gA0 + 64 * K + k0, lA + 4096);
    GLL16(gB0 + k0, lB);
    GLL16(gB0 + 64 * K + k0, lB + 4096);
    __syncthreads();
    bf16x8 af[4], bfr[4];
#pragma unroll
    for (int i = 0; i < 4; ++i) {
      af[i] = *(const bf16x8*)&As[(wm * 64 + i * 16 + lr) * 32 + lg * 8];
      bfr[i] = *(const bf16x8*)&Bs[(wn * 64 + i * 16 + lr) * 32 + lg * 8];
    }
#pragma unroll
    for (int i = 0; i < 4; ++i)
#pragma unroll
      for (int j = 0; j < 4; ++j)
        acc[i][j] = MFMA16(af[i], bfr[j], acc[i][j]);
  }
#pragma unroll
  for (int i = 0; i < 4; ++i) {
#pragma unroll
    for (int j = 0; j < 4; ++j) {
      int n = n0 + wn * 64 + j * 16 + lr;
      int mb = m0 + wm * 64 + i * 16 + lg * 4;
#pragma unroll
      for (int r = 0; r < 4; ++r)
        out[(mb + r) * 1024 + n] = acc[i][j][r];
    }
  }
}

extern "C" void kernel_launch(void* const* d_in, const int* in_sizes, int n_in,
                              void* d_out, int out_size, void* d_ws, size_t ws_size,
                              hipStream_t stream) {
  const float* x       = (const float*)d_in[0];
  const float* amask   = (const float*)d_in[1];
  const float* w_qt    = (const float*)d_in[2];
  const float* w_kt    = (const float*)d_in[3];
  const float* w_qs    = (const float*)d_in[4];
  const float* w_ks    = (const float*)d_in[5];
  const float* w_sigma = (const float*)d_in[6];
  const float* w_v     = (const float*)d_in[7];
  const float* w_o     = (const float*)d_in[8];

  char* ws = (char*)d_ws;
  unsigned short* xb    = (unsigned short*)ws;                    // 8 MB
  unsigned short* wcat  = (unsigned short*)(ws + 8388608);        // 6 MB
  unsigned short* wob   = (unsigned short*)(ws + 14680064);       // 2 MB
  unsigned short* qb    = (unsigned short*)(ws + 16777216);       // 8 MB
  unsigned short* kfrag = (unsigned short*)(ws + 25165824);       // 8 MB
  unsigned short* vfrag = (unsigned short*)(ws + 33554432);       // 8 MB
  unsigned short* ao    = (unsigned short*)(ws + 41943040);       // 8 MB

  float* outp = (float*)d_out;
  float* probs = outp + 4194304;

  convert_kernel<<<2048, 256, 0, stream>>>(x, w_qt, w_kt, w_qs, w_ks, w_v, w_o, xb, wcat, wob);
  gemm_qkv<<<dim3(32, 24), 256, 0, stream>>>(xb, wcat, amask, qb, kfrag, vfrag);
  attn_kernel<<<2048, 256, 0, stream>>>(qb, kfrag, vfrag, amask, w_sigma, probs, ao);
  gemm_oproj<<<dim3(32, 8), 256, 0, stream>>>(ao, wob, outp);
}

// Round 15
// 272.916 us; speedup vs baseline: 1.1261x; 1.1261x over previous
//
#include <hip/hip_runtime.h>

typedef __bf16 bf16x8 __attribute__((ext_vector_type(8)));
typedef float f32x4 __attribute__((ext_vector_type(4)));
typedef float f32x16 __attribute__((ext_vector_type(16)));
typedef short short4v __attribute__((ext_vector_type(4)));
typedef unsigned short ushort8 __attribute__((ext_vector_type(8)));
typedef unsigned int uint4v __attribute__((ext_vector_type(4)));

#define AS1 __attribute__((address_space(1)))
#define AS3 __attribute__((address_space(3)))
#define GLL16(g, l) __builtin_amdgcn_global_load_lds((const AS1 void*)(g), (AS3 void*)(l), 16, 0, 0)
#define MFMA16(a, b, c) __builtin_amdgcn_mfma_f32_16x16x32_bf16((a), (b), (c), 0, 0, 0)
#define MFMA32(a, b, c) __builtin_amdgcn_mfma_f32_32x32x16_bf16((a), (b), (c), 0, 0, 0)
#define L2E 1.44269504f

__device__ __forceinline__ unsigned short f2bf(float f) {
  unsigned int u = __builtin_bit_cast(unsigned int, f);
  u = (u + 0x7fffu + ((u >> 16) & 1u)) >> 16;
  return (unsigned short)u;
}

__device__ __forceinline__ unsigned int cvtpk_bf16(float lo, float hi) {
  unsigned int r;
  asm("v_cvt_pk_bf16_f32 %0, %1, %2" : "=v"(r) : "v"(lo), "v"(hi));
  return r;
}

// ---------------- convert: f32 -> bf16 (x, concat weights, w_o) ----------------
__global__ void convert_kernel(const float* __restrict__ x,
                               const float* __restrict__ w_qt, const float* __restrict__ w_kt,
                               const float* __restrict__ w_qs, const float* __restrict__ w_ks,
                               const float* __restrict__ w_v, const float* __restrict__ w_o,
                               unsigned short* __restrict__ xb, unsigned short* __restrict__ wcat,
                               unsigned short* __restrict__ wob) {
  const int NX = 4096 * 1024, NW = 3072 * 1024, NO = 1024 * 1024;
  int stride = gridDim.x * blockDim.x;
  for (int i = blockIdx.x * blockDim.x + threadIdx.x; i < NX + NW + NO; i += stride) {
    if (i < NX) {
      xb[i] = f2bf(x[i]);
    } else if (i < NX + NW) {
      int j = i - NX;
      int n = j >> 10, k = j & 1023;
      const float* src;
      if (n < 256)        src = w_qt + n * 1024;
      else if (n < 1024)  src = w_qs + (n - 256) * 1024;
      else if (n < 1280)  src = w_kt + (n - 1024) * 1024;
      else if (n < 2048)  src = w_ks + (n - 1280) * 1024;
      else                src = w_v + (n - 2048) * 1024;
      wcat[j] = f2bf(src[k]);
    } else {
      int j = i - NX - NW;
      wob[j] = f2bf(w_o[j]);
    }
  }
}

// ---------------- GEMM 1: X*(Wq|Wk|Wv)^T -> Q (B,H,L,64), Kfrag, Vfrag (MFMA-fragment layout) ----------------
// kfrag[bh][cg][m][lane][e]: element = K[bh][cg*32 + (lane&31)][m*16 + (lane>>5)*8 + e]
// vfrag[bh][cg][kh*2+dh][lane][e]: element = V'[bh][cg*32 + kh*16 + (lane>>5)*8 + e][dh*32 + (lane&31)]
//   (V' = V * e^mask, folded)
__global__ __launch_bounds__(256) void gemm_qkv(const unsigned short* __restrict__ A,
                                                const unsigned short* __restrict__ Bw,
                                                const float* __restrict__ amask,
                                                unsigned short* __restrict__ qb,
                                                unsigned short* __restrict__ kfrag,
                                                unsigned short* __restrict__ vfrag) {
  __shared__ unsigned short As[128 * 32];
  __shared__ unsigned short Bs[128 * 32];
  const int t = threadIdx.x;
  const int lane = t & 63, wid = t >> 6;
  const int wm = wid >> 1, wn = wid & 1;
  const int lr = lane & 15, lg = lane >> 4;
  const int m0 = blockIdx.x * 128, n0 = blockIdx.y * 128;
  const int K = 1024;
  f32x4 acc[4][4] = {};
  const unsigned short* gA0 = A + (m0 + (t >> 2)) * K + (t & 3) * 8;
  const unsigned short* gB0 = Bw + (n0 + (t >> 2)) * K + (t & 3) * 8;
  char* lA = (char*)As + wid * 1024;
  char* lB = (char*)Bs + wid * 1024;
  for (int k0 = 0; k0 < K; k0 += 32) {
    __syncthreads();
    GLL16(gA0 + k0, lA);
    GLL16(gA0 + 64 * K + k0, lA + 4096);
    GLL16(gB0 + k0, lB);
    GLL16(gB0 + 64 * K + k0, lB + 4096);
    __syncthreads();
    bf16x8 af[4], bfr[4];
#pragma unroll
    for (int i = 0; i < 4; ++i) {
      af[i] = *(const bf16x8*)&As[(wm * 64 + i * 16 + lr) * 32 + lg * 8];
      bfr[i] = *(const bf16x8*)&Bs[(wn * 64 + i * 16 + lr) * 32 + lg * 8];
    }
#pragma unroll
    for (int i = 0; i < 4; ++i)
#pragma unroll
      for (int j = 0; j < 4; ++j)
        acc[i][j] = MFMA16(af[i], bfr[j], acc[i][j]);
  }
#pragma unroll
  for (int i = 0; i < 4; ++i) {
#pragma unroll
    for (int j = 0; j < 4; ++j) {
      int n = n0 + wn * 64 + j * 16 + lr;
      int mb = m0 + wm * 64 + i * 16 + lg * 4;
      int b = mb >> 11, l = mb & 2047;   // tokens mb..mb+3 share b (128 | 2048)
      f32x4 v = acc[i][j];
      if (n < 1024) {
        // Q: (B,H,L,64)
        int h = n >> 6, d = n & 63;
#pragma unroll
        for (int r = 0; r < 4; ++r)
          qb[((b * 16 + h) * 2048 + l + r) * 64 + d] = f2bf(v[r]);
      } else if (n < 2048) {
        // K fragment layout
        int nn = n - 1024;
        int h = nn >> 6, d = nn & 63;
        int mfr = d >> 4, hi2 = (d >> 3) & 1, e = d & 7;
#pragma unroll
        for (int r = 0; r < 4; ++r) {
          int lr2 = l + r;
          int cgr = lr2 >> 5, ck = lr2 & 31;
          size_t idx = ((size_t)((b * 16 + h) * 64 + cgr) * 4 + mfr) * 512 + (hi2 * 32 + ck) * 8 + e;
          kfrag[idx] = f2bf(v[r]);
        }
      } else {
        // V' fragment layout (scaled by e^mask); 4 tokens contiguous within one lane's 8 elems
        int nn = n - 2048;
        int h = nn >> 6, d = nn & 63;
        int dh = d >> 5, dcol = d & 31;
        int kk = l & 31;
        int kh = kk >> 4, hi2 = (kk >> 3) & 1, i0 = kk & 7;
        const float* mrow = amask + b * 2048 + l;
        size_t idx = ((size_t)((b * 16 + h) * 64 + (l >> 5)) * 4 + (kh * 2 + dh)) * 512
                     + (hi2 * 32 + dcol) * 8 + i0;
        short4v pk;
#pragma unroll
        for (int r = 0; r < 4; ++r)
          pk[r] = (short)f2bf(v[r] * __expf(mrow[r]));
        *(short4v*)&vfrag[idx] = pk;
      }
    }
  }
}

// ---------------- attention v9 (champion): fragment-direct loads, dual-orientation QK ----------------
// Block = 32 q-rows of one bh; 4 waves, wave w owns tiles cg in [w*16, w*16+16).
__global__ __launch_bounds__(256, 3) void attn_kernel(const unsigned short* __restrict__ qb,
                                                      const unsigned short* __restrict__ kfrag,
                                                      const unsigned short* __restrict__ vfrag,
                                                      const float* __restrict__ mask,
                                                      const float* __restrict__ w_sigma,
                                                      float* __restrict__ probs,
                                                      unsigned short* __restrict__ ao) {
  __shared__ __align__(16) float pvacc[2048];
  __shared__ float psum[4][32];
  __shared__ float rsum[32];
  const int t = threadIdx.x;
  const int lane = t & 63, w = t >> 6;
  const int col = lane & 31, hi = lane >> 5;
  const int s = blockIdx.x;
  const int bh = (s & 7) * 4 + ((s >> 3) >> 6);
  const int q0 = ((s >> 3) & 63) * 32;
  const int b = bh >> 4, h = bh & 15;
  const float sigma = 1.0f / (1.0f + __expf(-w_sigma[0]));
  const float fac2 = ((h < 4) ? (-sigma * 0.125f) : 0.125f) * L2E;
  const float* maskb = mask + b * 2048;
  const int cg0 = w * 16;

  const unsigned short* kfb = kfrag + (size_t)bh * 131072;
  const unsigned short* vfb = vfrag + (size_t)bh * 131072;

  for (int i = t; i < 2048; i += 256) pvacc[i] = 0.0f;

  // Q fragments (one-time gather)
  bf16x8 qf[4];
  {
    const unsigned short* qp = qb + (size_t)(bh * 2048 + q0 + col) * 64 + hi * 8;
#pragma unroll
    for (int m = 0; m < 4; ++m) qf[m] = *(const bf16x8*)(qp + m * 16);
  }

  // ---- pass 1: rowsums ----
  float rs[16];
#pragma unroll
  for (int r = 0; r < 16; ++r) rs[r] = 0.f;
  for (int c = 0; c < 16; ++c) {
    int cg = cg0 + c;
    const unsigned short* kp = kfb + (size_t)cg * 2048 + lane * 8;
    bf16x8 kf0 = *(const bf16x8*)(kp);
    bf16x8 kf1 = *(const bf16x8*)(kp + 512);
    bf16x8 kf2 = *(const bf16x8*)(kp + 1024);
    bf16x8 kf3 = *(const bf16x8*)(kp + 1536);
    float mv2 = maskb[cg * 32 + col] * L2E;
    f32x16 sacc = {};
    sacc = MFMA32(qf[0], kf0, sacc);
    sacc = MFMA32(qf[1], kf1, sacc);
    sacc = MFMA32(qf[2], kf2, sacc);
    sacc = MFMA32(qf[3], kf3, sacc);
#pragma unroll
    for (int r = 0; r < 16; ++r) rs[r] += exp2f(sacc[r] * fac2 + mv2);
  }
#pragma unroll
  for (int o = 1; o < 32; o <<= 1)
#pragma unroll
    for (int r = 0; r < 16; ++r) rs[r] += __shfl_xor(rs[r], o);
  if (col == 0) {
#pragma unroll
    for (int r = 0; r < 16; ++r) psum[w][(r & 3) + 8 * (r >> 2) + 4 * hi] = rs[r];
  }
  __syncthreads();
  if (t < 32) rsum[t] = -log2f(psum[0][t] + psum[1][t] + psum[2][t] + psum[3][t]);
  __syncthreads();

  float rws_l[16];
#pragma unroll
  for (int r = 0; r < 16; ++r) rws_l[r] = rsum[(r & 3) + 8 * (r >> 2) + 4 * hi];
  const float rws_t = rsum[col];

  // ---- pass 2: dual-orientation QK, direct probs stores, in-reg PV fragments ----
  f32x16 oacc0 = {}, oacc1 = {};
  float* pp = probs + (size_t)(bh * 2048 + q0) * 2048;
  for (int c = 0; c < 16; ++c) {
    int cg = cg0 + c;
    const unsigned short* kp = kfb + (size_t)cg * 2048 + lane * 8;
    const unsigned short* vp = vfb + (size_t)cg * 2048 + lane * 8;
    bf16x8 kf0 = *(const bf16x8*)(kp);
    bf16x8 kf1 = *(const bf16x8*)(kp + 512);
    bf16x8 kf2 = *(const bf16x8*)(kp + 1024);
    bf16x8 kf3 = *(const bf16x8*)(kp + 1536);
    bf16x8 vf0 = *(const bf16x8*)(vp);
    bf16x8 vf1 = *(const bf16x8*)(vp + 512);
    bf16x8 vf2 = *(const bf16x8*)(vp + 1024);
    bf16x8 vf3 = *(const bf16x8*)(vp + 1536);
    float mv2 = maskb[cg * 32 + col] * L2E;
    f32x16 sn = {}, st_ = {};
    sn = MFMA32(qf[0], kf0, sn);  st_ = MFMA32(kf0, qf[0], st_);
    sn = MFMA32(qf[1], kf1, sn);  st_ = MFMA32(kf1, qf[1], st_);
    sn = MFMA32(qf[2], kf2, sn);  st_ = MFMA32(kf2, qf[2], st_);
    sn = MFMA32(qf[3], kf3, sn);  st_ = MFMA32(kf3, qf[3], st_);
    // n-side: normalized probs (exact mask)
    float pn[16];
#pragma unroll
    for (int r = 0; r < 16; ++r) pn[r] = exp2f(sn[r] * fac2 + (rws_l[r] + mv2));
    // t-side: mask folded into V'; clamp for general-mask safety
    float pt[16];
#pragma unroll
    for (int r = 0; r < 16; ++r) pt[r] = exp2f(fminf(st_[r] * fac2 + rws_t, 60.0f));
    unsigned int A0 = cvtpk_bf16(pt[0], pt[1]),   B0 = cvtpk_bf16(pt[4], pt[5]);
    unsigned int C0 = cvtpk_bf16(pt[2], pt[3]),   D0 = cvtpk_bf16(pt[6], pt[7]);
    unsigned int E0 = cvtpk_bf16(pt[8], pt[9]),   F0 = cvtpk_bf16(pt[12], pt[13]);
    unsigned int G0 = cvtpk_bf16(pt[10], pt[11]), H0 = cvtpk_bf16(pt[14], pt[15]);
    asm("v_permlane32_swap_b32 %0, %1" : "+v"(A0), "+v"(B0));
    asm("v_permlane32_swap_b32 %0, %1" : "+v"(C0), "+v"(D0));
    asm("v_permlane32_swap_b32 %0, %1" : "+v"(E0), "+v"(F0));
    asm("v_permlane32_swap_b32 %0, %1" : "+v"(G0), "+v"(H0));
    uint4v u1; u1[0] = A0; u1[1] = C0; u1[2] = B0; u1[3] = D0;
    uint4v u2; u2[0] = E0; u2[1] = G0; u2[2] = F0; u2[3] = H0;
    bf16x8 frag1 = __builtin_bit_cast(bf16x8, u1);
    bf16x8 frag2 = __builtin_bit_cast(bf16x8, u2);
    // PV: oacc[dh] += frag[kh] * vf[kh*2+dh]
    oacc0 = MFMA32(frag1, vf0, oacc0);
    oacc1 = MFMA32(frag1, vf1, oacc1);
    oacc0 = MFMA32(frag2, vf2, oacc0);
    oacc1 = MFMA32(frag2, vf3, oacc1);
    // probs stores (two 128B segments per instr)
    float* pr = pp + cg * 32 + col;
#pragma unroll
    for (int r = 0; r < 16; ++r) {
      int row = (r & 3) + 8 * (r >> 2) + 4 * hi;
      __builtin_nontemporal_store(pn[r], pr + (size_t)row * 2048);
    }
  }

  // ---- merge PV partials across waves ----
  __syncthreads();
#pragma unroll
  for (int r = 0; r < 16; ++r) {
    int row = (r & 3) + 8 * (r >> 2) + 4 * hi;
    atomicAdd(&pvacc[row * 64 + col], oacc0[r]);
    atomicAdd(&pvacc[row * 64 + 32 + col], oacc1[r]);
  }
  __syncthreads();
  {
    int row = t >> 3, c8 = (t & 7) * 8;
    f32x4 v0 = *(const f32x4*)&pvacc[row * 64 + c8];
    f32x4 v1 = *(const f32x4*)&pvacc[row * 64 + c8 + 4];
    ushort8 o;
#pragma unroll
    for (int i = 0; i < 4; ++i) {
      o[i] = f2bf(v0[i]);
      o[i + 4] = f2bf(v1[i]);
    }
    *(ushort8*)&ao[((b * 2048) + q0 + row) * 1024 + h * 64 + c8] = o;
  }
}

// ---------------- GEMM 2: AO(4096x1024) * Wo(1024x1024)^T -> out f32 ----------------
__global__ __launch_bounds__(256) void gemm_oproj(const unsigned short* __restrict__ A,
                                                  const unsigned short* __restrict__ Bw,
                                                  float* __restrict__ out) {
  __shared__ unsigned short As[128 * 32];
  __shared__ unsigned short Bs[128 * 32];
  const int t = threadIdx.x;
  const int lane = t & 63, wid = t >> 6;
  const int wm = wid >> 1, wn = wid & 1;
  const int lr = lane & 15, lg = lane >> 4;
  const int m0 = blockIdx.x * 128, n0 = blockIdx.y * 128;
  const int K = 1024;
  f32x4 acc[4][4] = {};
  const unsigned short* gA0 = A + (m0 + (t >> 2)) * K + (t & 3) * 8;
  const unsigned short* gB0 = Bw + (n0 + (t >> 2)) * K + (t & 3) * 8;
  char* lA = (char*)As + wid * 1024;
  char* lB = (char*)Bs + wid * 1024;
  for (int k0 = 0; k0 < K; k0 += 32) {
    __syncthreads();
    GLL16(gA0 + k0, lA);
    GLL16(gA0 + 64 * K + k0, lA + 4096);
    GLL16(gB0 + k0, lB);
    GLL16(gB0 + 64 * K + k0, lB + 4096);
    __syncthreads();
    bf16x8 af[4], bfr[4];
#pragma unroll
    for (int i = 0; i < 4; ++i) {
      af[i] = *(const bf16x8*)&As[(wm * 64 + i * 16 + lr) * 32 + lg * 8];
      bfr[i] = *(const bf16x8*)&Bs[(wn * 64 + i * 16 + lr) * 32 + lg * 8];
    }
#pragma unroll
    for (int i = 0; i < 4; ++i)
#pragma unroll
      for (int j = 0; j < 4; ++j)
        acc[i][j] = MFMA16(af[i], bfr[j], acc[i][j]);
  }
#pragma unroll
  for (int i = 0; i < 4; ++i) {
#pragma unroll
    for (int j = 0; j < 4; ++j) {
      int n = n0 + wn * 64 + j * 16 + lr;
      int mb = m0 + wm * 64 + i * 16 + lg * 4;
#pragma unroll
      for (int r = 0; r < 4; ++r)
        out[(mb + r) * 1024 + n] = acc[i][j][r];
    }
  }
}

extern "C" void kernel_launch(void* const* d_in, const int* in_sizes, int n_in,
                              void* d_out, int out_size, void* d_ws, size_t ws_size,
                              hipStream_t stream) {
  const float* x       = (const float*)d_in[0];
  const float* amask   = (const float*)d_in[1];
  const float* w_qt    = (const float*)d_in[2];
  const float* w_kt    = (const float*)d_in[3];
  const float* w_qs    = (const float*)d_in[4];
  const float* w_ks    = (const float*)d_in[5];
  const float* w_sigma = (const float*)d_in[6];
  const float* w_v     = (const float*)d_in[7];
  const float* w_o     = (const float*)d_in[8];

  char* ws = (char*)d_ws;
  unsigned short* xb    = (unsigned short*)ws;                    // 8 MB
  unsigned short* wcat  = (unsigned short*)(ws + 8388608);        // 6 MB
  unsigned short* wob   = (unsigned short*)(ws + 14680064);       // 2 MB
  unsigned short* qb    = (unsigned short*)(ws + 16777216);       // 8 MB
  unsigned short* kfrag = (unsigned short*)(ws + 25165824);       // 8 MB
  unsigned short* vfrag = (unsigned short*)(ws + 33554432);       // 8 MB
  unsigned short* ao    = (unsigned short*)(ws + 41943040);       // 8 MB

  float* outp = (float*)d_out;
  float* probs = outp + 4194304;

  convert_kernel<<<2048, 256, 0, stream>>>(x, w_qt, w_kt, w_qs, w_ks, w_v, w_o, xb, wcat, wob);
  gemm_qkv<<<dim3(32, 24), 256, 0, stream>>>(xb, wcat, amask, qb, kfrag, vfrag);
  attn_kernel<<<2048, 256, 0, stream>>>(qb, kfrag, vfrag, amask, w_sigma, probs, ao);
  gemm_oproj<<<dim3(32, 8), 256, 0, stream>>>(ao, wob, outp);
}